// Round 1
// baseline (755.072 us; speedup 1.0000x reference)
//
#include <hip/hip_runtime.h>

// B=2, H=16, L=S=2048, E=D=64. queries/keys unused by the reference math.
constexpr int Bc = 2, Hc = 16, Lc = 2048, Sc = 2048, Dc = 64;
constexpr int TL = 16;    // rows per block
constexpr int TJ = 128;   // j-tile width
constexpr int NT = 256;   // threads per block
constexpr int PP = 136;   // ptile pitch (bf16 elems): 272 B -> 2-way bank alias (free)

typedef __attribute__((ext_vector_type(8))) short short8;  // 8 bf16 (4 VGPRs)
typedef __attribute__((ext_vector_type(4))) float f32x4;

__device__ __forceinline__ unsigned short f2bf(float x) {
  unsigned u = __float_as_uint(x);
  u += 0x7FFF + ((u >> 16) & 1);   // RNE
  return (unsigned short)(u >> 16);
}
__device__ __forceinline__ float wave_max(float v) {
#pragma unroll
  for (int m = 32; m >= 1; m >>= 1) v = fmaxf(v, __shfl_xor(v, m));
  return v;
}
__device__ __forceinline__ float wave_sum(float v) {
#pragma unroll
  for (int m = 32; m >= 1; m >>= 1) v += __shfl_xor(v, m);
  return v;
}
__device__ __forceinline__ float half_sum(float v) {  // 32-lane halves
#pragma unroll
  for (int m = 16; m >= 1; m >>= 1) v += __shfl_xor(v, m);
  return v;
}

// V [B,S,H,D] fp32 -> Vt [B,H,D,S] bf16 (so main kernel reads V along j at fixed d)
__global__ __launch_bounds__(256) void transpose_v(const float* __restrict__ V,
                                                   unsigned short* __restrict__ Vt) {
  const int st = blockIdx.x, h = blockIdx.y, b = blockIdx.z;
  const int s0 = st * 64, tid = threadIdx.x;
  __shared__ float t[64][65];
  const float* vb = V + ((size_t)(b * Sc + s0) * Hc + h) * Dc;
#pragma unroll
  for (int e = 0; e < 4; ++e) {
    int f = tid + 256 * e, si = f >> 4, dq = f & 15;
    float4 v = *(const float4*)(vb + (size_t)si * Hc * Dc + dq * 4);
    t[si][dq * 4 + 0] = v.x; t[si][dq * 4 + 1] = v.y;
    t[si][dq * 4 + 2] = v.z; t[si][dq * 4 + 3] = v.w;
  }
  __syncthreads();
  const int d = tid >> 2, sq = tid & 3;
  unsigned pk[8];
#pragma unroll
  for (int k = 0; k < 8; ++k) {
    int s = sq * 16 + 2 * k;
    pk[k] = (unsigned)f2bf(t[s][d]) | ((unsigned)f2bf(t[s + 1][d]) << 16);
  }
  unsigned short* dst = Vt + ((size_t)((b * Hc + h) * Dc + d)) * Sc + s0 + sq * 16;
  uint4* dv = (uint4*)dst;
  dv[0] = make_uint4(pk[0], pk[1], pk[2], pk[3]);
  dv[1] = make_uint4(pk[4], pk[5], pk[6], pk[7]);
}

__global__ __launch_bounds__(NT) void zzy_attn(
    const unsigned short* __restrict__ Vt,  // [B,H,D,S] bf16
    const float* __restrict__ scores,       // [B,H,L,S] fp32
    float* __restrict__ out) {              // [B,L,H,D] fp32
  const int lt = blockIdx.x, h = blockIdx.y, b = blockIdx.z;
  const int l0 = lt * TL, tid = threadIdx.x;
  const int lane = tid & 63, wv = tid >> 6;

  __shared__ __align__(16) unsigned short pt[2][TL * PP];  // 2 x 4352 B
  __shared__ float s_m1[TL], s_iz1[TL], z2acc[TL];

  const size_t score_bh = (size_t)(b * Hc + h) * Lc * Sc;

  // ---- Phase 1: per-wave first-softmax stats over FULL rows (no barriers) ----
#pragma unroll
  for (int t = 0; t < 4; ++t) {
    const int r = wv * 4 + t;
    const float4* row = (const float4*)(scores + score_bh + (size_t)(l0 + r) * Sc);
    float4 v[8];
#pragma unroll
    for (int e = 0; e < 8; ++e) v[e] = row[lane + 64 * e];
    float m = -1e30f;
#pragma unroll
    for (int e = 0; e < 8; ++e)
      m = fmaxf(m, fmaxf(fmaxf(v[e].x, v[e].y), fmaxf(v[e].z, v[e].w)));
    m = wave_max(m);
    float s = 0.f;
#pragma unroll
    for (int e = 0; e < 8; ++e)
      s += __expf(v[e].x - m) + __expf(v[e].y - m) +
           __expf(v[e].z - m) + __expf(v[e].w - m);
    s = wave_sum(s);
    if (lane == 0) { s_m1[r] = m; s_iz1[r] = 1.0f / s; }
  }
  __syncthreads();

  // ---- Phase 2: j-tiles; P = exp(exp(s-m1)/Z1) masked; MFMA O += P @ V ----
  // One barrier per tile (double-buffered P), B-fragments direct from global Vt
  // (same bytes the old vT staging produced; Vt slice is L2-resident).
  const int m16 = lane & 15, q = lane >> 4;
  f32x4 acc = {0.f, 0.f, 0.f, 0.f};
  float z0 = 0.f, z1 = 0.f;               // register Z2 partials (rows r0, r0+8)
  const int r0 = tid >> 5;

  // P-compute mapping: this thread owns rows r0 / r0+8, col-quad pjc
  const int pjc = tid & 31;
  const int jq = pjc * 4;
  const float* srowA = scores + score_bh + (size_t)(l0 + r0) * Sc + jq;
  const float* srowB = srowA + (size_t)8 * Sc;
  const float m1a = s_m1[r0],     iza = s_iz1[r0];
  const float m1b = s_m1[r0 + 8], izb = s_iz1[r0 + 8];
  const int la = l0 + r0, lb = la + 8;

  // MFMA B operand: direct global row for this lane (d = 16*wv + m16)
  const unsigned short* vrow =
      Vt + ((size_t)((b * Hc + h) * Dc + 16 * wv + m16)) * Sc + q * 8;

  const int ntiles = (l0 + TL - 1) / TJ + 1;  // causal tile skip

  // prefetch tile 0 scores into registers
  float4 sA = *(const float4*)(srowA);
  float4 sB = *(const float4*)(srowB);

  for (int jt = 0; jt < ntiles; ++jt) {
    const int j0 = jt * TJ;
    unsigned short* pb = pt[jt & 1];

    // P tile (bf16) from prefetched registers + register Z2 accumulation
    {
      const int jb = j0 + jq;
      float p0 = (jb + 0 <= la) ? __expf(__expf(sA.x - m1a) * iza) : 0.f;
      float p1 = (jb + 1 <= la) ? __expf(__expf(sA.y - m1a) * iza) : 0.f;
      float p2 = (jb + 2 <= la) ? __expf(__expf(sA.z - m1a) * iza) : 0.f;
      float p3 = (jb + 3 <= la) ? __expf(__expf(sA.w - m1a) * iza) : 0.f;
      z0 += p0 + p1 + p2 + p3;
      uint2 pk;
      pk.x = (unsigned)f2bf(p0) | ((unsigned)f2bf(p1) << 16);
      pk.y = (unsigned)f2bf(p2) | ((unsigned)f2bf(p3) << 16);
      *(uint2*)&pb[r0 * PP + jq] = pk;

      float q0 = (jb + 0 <= lb) ? __expf(__expf(sB.x - m1b) * izb) : 0.f;
      float q1 = (jb + 1 <= lb) ? __expf(__expf(sB.y - m1b) * izb) : 0.f;
      float q2 = (jb + 2 <= lb) ? __expf(__expf(sB.z - m1b) * izb) : 0.f;
      float q3 = (jb + 3 <= lb) ? __expf(__expf(sB.w - m1b) * izb) : 0.f;
      z1 += q0 + q1 + q2 + q3;
      pk.x = (unsigned)f2bf(q0) | ((unsigned)f2bf(q1) << 16);
      pk.y = (unsigned)f2bf(q2) | ((unsigned)f2bf(q3) << 16);
      *(uint2*)&pb[(r0 + 8) * PP + jq] = pk;
    }

    // issue next tile's score loads (stay in flight across the barrier)
    if (jt + 1 < ntiles) {
      sA = *(const float4*)(srowA + j0 + TJ);
      sB = *(const float4*)(srowB + j0 + TJ);
    }

    __syncthreads();

    // MFMA: wave wv owns output cols 16*wv..16*wv+15; K=128 in 4 steps
#pragma unroll
    for (int ks = 0; ks < 4; ++ks) {
      short8 af = *(const short8*)&pb[m16 * PP + ks * 32 + q * 8];
      short8 bf = *(const short8*)(vrow + j0 + ks * 32);
      acc = __builtin_amdgcn_mfma_f32_16x16x32_bf16(af, bf, acc, 0, 0, 0);
    }
    // no second barrier: next iteration writes the other P buffer, and its
    // pre-MFMA barrier orders any same-buffer reuse two tiles out.
  }

  // ---- Z2 finalize: shuffle-reduce register partials, one write per row ----
  float zz0 = half_sum(z0), zz1 = half_sum(z1);
  if ((tid & 31) == 0) { z2acc[r0] = zz0; z2acc[r0 + 8] = zz1; }
  __syncthreads();

  // ---- Epilogue: C layout col=lane&15, row=q*4+reg; normalize and store ----
#pragma unroll
  for (int reg = 0; reg < 4; ++reg) {
    int row = q * 4 + reg;
    float o = acc[reg] / z2acc[row];
    out[((size_t)(b * Lc + l0 + row) * Hc + h) * Dc + 16 * wv + m16] = o;
  }
}

extern "C" void kernel_launch(void* const* d_in, const int* in_sizes, int n_in,
                              void* d_out, int out_size, void* d_ws,
                              size_t ws_size, hipStream_t stream) {
  // inputs: 0=queries (unused), 1=keys (unused), 2=values, 3=scores
  const float* values = (const float*)d_in[2];
  const float* scores = (const float*)d_in[3];
  float* out = (float*)d_out;
  unsigned short* Vt = (unsigned short*)d_ws;  // 8 MiB bf16 scratch

  transpose_v<<<dim3(Sc / 64, Hc, Bc), 256, 0, stream>>>(values, Vt);
  zzy_attn<<<dim3(Lc / TL, Hc, Bc), NT, 0, stream>>>(Vt, scores, out);
}